// Round 14
// baseline (169.606 us; speedup 1.0000x reference)
//
#include <hip/hip_runtime.h>
#include <stdint.h>

#define NB   4
#define SEQ  4096
#define DIM  256
#define NROW (NB*SEQ)   // 16384

using bf16x8   = __attribute__((ext_vector_type(8))) __bf16;
using half8    = __attribute__((ext_vector_type(8))) _Float16;
using f32x4    = __attribute__((ext_vector_type(4))) float;
using f32x16   = __attribute__((ext_vector_type(16))) float;
using u32x4    = __attribute__((ext_vector_type(4))) unsigned int;
using ushort4t = __attribute__((ext_vector_type(4))) unsigned short;

#define RLOG2E 1.44269504088896340736f   // 1/ln2, folded into Qf by proj

__device__ __forceinline__ unsigned f2bf(float f){
    unsigned u = __builtin_bit_cast(unsigned, f);
    return (u + 0x7fffu + ((u >> 16) & 1u)) >> 16;   // RNE to bf16 bits
}
__device__ __forceinline__ float bf2f(unsigned b){
    return __builtin_bit_cast(float, b << 16);
}

#define MFMA(a,b,c)   __builtin_amdgcn_mfma_f32_16x16x32_bf16((a),(b),(c),0,0,0)
#define MFMAQK(a,b,c) __builtin_amdgcn_mfma_f32_32x32x16_f16((a),(b),(c),0,0,0)
#define MFMAPV(a,b,c) __builtin_amdgcn_mfma_f32_32x32x16_bf16((a),(b),(c),0,0,0)

// async global -> LDS, 16 B per lane. LDS dest = wave-uniform base + lane*16.
__device__ __forceinline__ void gld16(const void* g, void* l){
    __builtin_amdgcn_global_load_lds(
        (const __attribute__((address_space(1))) void*)g,
        (__attribute__((address_space(3))) void*)l, 16, 0, 0);
}

// Cross-half (lane i <-> i+32) reduce on the VALU pipe via permlane32_swap.
// R8 lesson: b must be forced into its OWN register (opaque asm) or CSE +
// tied "+v" constraints collapse both operands to one physreg -> in-place
// half-exchange (wrong). After swap(a,b): own value in one reg, cross-half
// value in the other.
__device__ __forceinline__ float xhalf_max(float x){
    unsigned a = __builtin_bit_cast(unsigned, x);
    unsigned b = a;
    asm volatile("" : "+v"(b));                       // force distinct reg
    asm volatile("v_permlane32_swap_b32 %0, %1" : "+v"(a), "+v"(b));
    return fmaxf(__builtin_bit_cast(float, a), __builtin_bit_cast(float, b));
}
__device__ __forceinline__ float xhalf_sum(float x){
    unsigned a = __builtin_bit_cast(unsigned, x);
    unsigned b = a;
    asm volatile("" : "+v"(b));                       // force distinct reg
    asm volatile("v_permlane32_swap_b32 %0, %1" : "+v"(a), "+v"(b));
    return __builtin_bit_cast(float, a) + __builtin_bit_cast(float, b);
}

// ---------------------------------------------------------------------------
// Kernel 1: W[k][n] fp32 -> FRAGMENT-ORDERED split bf16 planes.
//   o = ((((m*2+nh)*8+nt)*8+kc)*64 + lane)*8 + j
// ---------------------------------------------------------------------------
__global__ __launch_bounds__(256) void convert_w_kernel(
    const float* __restrict__ Wq, const float* __restrict__ Wk,
    const float* __restrict__ Wv,
    unsigned short* __restrict__ WtHi, unsigned short* __restrict__ WtLo)
{
    int mat = blockIdx.y;
    const float* W = (mat == 0) ? Wq : (mat == 1 ? Wk : Wv);
    int id = blockIdx.x * 256 + threadIdx.x;     // 0..65535
    int k = id >> 8, n = id & 255;
    float v = W[id];                              // W[k][n], coalesced read
    unsigned hi = f2bf(v);
    unsigned lo = f2bf(v - bf2f(hi));
    int nh = n >> 7, nt = (n >> 4) & 7, q16 = n & 15;
    int kc = k >> 5, g = (k >> 3) & 3, j = k & 7;
    int lane = g * 16 + q16;
    int o = ((((mat * 2 + nh) * 8 + nt) * 8 + kc) * 64 + lane) * 8 + j;
    WtHi[o] = (unsigned short)hi;
    WtLo[o] = (unsigned short)lo;
}

// ---------------------------------------------------------------------------
// Kernel 2: fused QKV projection (3-term bf16 split, fp32 accum).
// W fragments staged per-kc into 48 KB LDS via global_load_lds (R11/R12).
// CHANGE vs R13: Q is scaled by 1/ln2 at write -> flash scores arrive in
// log2 units and softmax uses exp2 (saves the x1.4427 mul per exp).
// Emits Qf/Kf fp16 [16384][256], Vt bf16 transposed [b][d][s].
// ---------------------------------------------------------------------------
__global__ __launch_bounds__(256) void proj_kernel(
    const float* __restrict__ x,
    const unsigned short* __restrict__ WtHi, const unsigned short* __restrict__ WtLo,
    const float* __restrict__ bq, const float* __restrict__ bk,
    const float* __restrict__ bv,
    _Float16* __restrict__ Qf, _Float16* __restrict__ Kf,
    unsigned short* __restrict__ Vt)
{
    __shared__ __align__(16) unsigned char wsm[49152];   // 48 frag-slots x 1 KB

    const int tid = threadIdx.x, lane = tid & 63, wid = tid >> 6;
    const int g = lane >> 4, q16 = lane & 15;
    const int mbase = blockIdx.x * 64 + wid * 16;
    const int nh = blockIdx.y;

    f32x4 acc[3][8];
    #pragma unroll
    for (int m = 0; m < 3; m++)
        #pragma unroll
        for (int n = 0; n < 8; n++) acc[m][n] = f32x4{0.f, 0.f, 0.f, 0.f};

    const float* xr = x + (mbase + q16) * DIM;

    for (int kc = 0; kc < 8; kc++) {
        __syncthreads();   // previous iteration's LDS reads complete
        // ---- stage this kc's 48 fragment-KB (3 mats x 8 nt x 2 planes) ----
        #pragma unroll
        for (int i = 0; i < 12; i++) {
            const int idx = wid * 12 + i;            // 0..47 = mat*16+nt*2+pl
            const int mat = idx >> 4, nt = (idx >> 1) & 7, pl = idx & 1;
            const size_t fb =
                ((size_t)(((mat * 2 + nh) * 8 + nt) * 8 + kc)) * 512 + lane * 8;
            gld16((pl ? WtLo : WtHi) + fb, wsm + idx * 1024);
        }

        // ---- x split hi/lo (overlaps the DMA) ----
        const float* p = xr + kc * 32 + 8 * g;
        f32x4 va = *(const f32x4*)p;
        f32x4 vb = *(const f32x4*)(p + 4);
        float fv[8] = {va[0], va[1], va[2], va[3], vb[0], vb[1], vb[2], vb[3]};
        unsigned hw[4], lw[4];
        #pragma unroll
        for (int i = 0; i < 4; i++) {
            unsigned h0 = f2bf(fv[2*i]),              h1 = f2bf(fv[2*i+1]);
            unsigned l0 = f2bf(fv[2*i]   - bf2f(h0)), l1 = f2bf(fv[2*i+1] - bf2f(h1));
            hw[i] = h0 | (h1 << 16);
            lw[i] = l0 | (l1 << 16);
        }
        bf16x8 ahi = __builtin_bit_cast(bf16x8, u32x4{hw[0], hw[1], hw[2], hw[3]});
        bf16x8 alo = __builtin_bit_cast(bf16x8, u32x4{lw[0], lw[1], lw[2], lw[3]});

        __syncthreads();   // DMA landed (barrier drains vmcnt)

        #pragma unroll
        for (int mat = 0; mat < 3; mat++) {
            #pragma unroll
            for (int nt = 0; nt < 8; nt++) {
                const int sidx = mat * 16 + nt * 2;
                bf16x8 bh = *(const bf16x8*)(wsm + sidx * 1024 + lane * 16);
                bf16x8 bl = *(const bf16x8*)(wsm + (sidx + 1) * 1024 + lane * 16);
                acc[mat][nt] = MFMA(ahi, bh, acc[mat][nt]);
                acc[mat][nt] = MFMA(ahi, bl, acc[mat][nt]);
                acc[mat][nt] = MFMA(alo, bh, acc[mat][nt]);
            }
        }
    }

    #pragma unroll
    for (int nt = 0; nt < 8; nt++) {
        int ncol = nh * 128 + nt * 16 + q16;
        {   // Q -> fp16, pre-scaled by 1/ln2 (exp2-domain softmax)
            float bb = bq[ncol];
            f32x4 c = acc[0][nt];
            #pragma unroll
            for (int r = 0; r < 4; r++)
                Qf[(size_t)(mbase + 4*g + r) * DIM + ncol] =
                    (_Float16)((c[r] + bb) * RLOG2E);
        }
        {   // K -> fp16
            float bb = bk[ncol];
            f32x4 c = acc[1][nt];
            #pragma unroll
            for (int r = 0; r < 4; r++)
                Kf[(size_t)(mbase + 4*g + r) * DIM + ncol] = (_Float16)(c[r] + bb);
        }
        {   // V -> plain transposed bf16 Vt[b][d][s]
            float bb = bv[ncol];
            f32x4 c = acc[2][nt];
            ushort4t pk;
            #pragma unroll
            for (int r = 0; r < 4; r++) pk[r] = (unsigned short)f2bf(c[r] + bb);
            int m0 = mbase + 4 * g;
            int bat = m0 >> 12, s0 = m0 & 4095;
            *(ushort4t*)(Vt + (size_t)(bat * DIM + ncol) * SEQ + s0) = pk;
        }
    }
}

// ---------------------------------------------------------------------------
// Kernel 3: flash attention — R13 structure (known-best).
// CHANGES vs R13 (chain-shortening only, no memory-op reordering):
//  (1) softmax in exp2 domain (scores pre-scaled by 1/ln2 in Qf) ->
//      exp2f = bare v_exp_f32, no x1.4427 mul; sc likewise.
//  (2) pm and ps computed via 4-deep pairwise trees instead of 15/16-deep
//      serial chains (-~90 dependent cycles per subtile).
// SQ_LDS_BANK_CONFLICT == 8388608 is STRUCTURAL: 4 extra cy per
// ds_read_b128 (m134's 12 cy/read) — not fixable by swizzle; ignore it.
// ---------------------------------------------------------------------------
#define KLDS  0
#define VLDS  32768
#define BUFSZ 65536

__global__ __launch_bounds__(512, 1) void flash_kernel(
    const _Float16* __restrict__ Qf, const _Float16* __restrict__ Kf,
    const unsigned short* __restrict__ Vt,
    unsigned short* __restrict__ O0, unsigned short* __restrict__ O1,
    unsigned short* __restrict__ O2, unsigned short* __restrict__ O3,
    float2* __restrict__ ml0, float2* __restrict__ ml1,
    float2* __restrict__ ml2, float2* __restrict__ ml3)
{
    __shared__ __align__(16) unsigned char smem[131072];

    const int tid = threadIdx.x, lane = tid & 63, wid = tid >> 6;
    const int r32 = lane & 31, h = lane >> 5;
    const int qrow0 = blockIdx.x * 256;
    const int b = qrow0 >> 12;
    const int split = blockIdx.y;
    const int kvbase = split * 1024;
    const int stp = wid & 1;          // sub-tile phase stagger per wave

    // --- Q fragments: B-operand, col q = r32, k = 16s + 8h + j ---
    half8 qf[16];
    {
        const _Float16* qp = Qf + (size_t)(qrow0 + wid * 32 + r32) * DIM;
        #pragma unroll
        for (int s = 0; s < 16; s++)
            qf[s] = *(const half8*)(qp + s * 16 + h * 8);
    }

    f32x16 o[8];
    #pragma unroll
    for (int i = 0; i < 8; i++)
        #pragma unroll
        for (int j = 0; j < 16; j++) o[i][j] = 0.f;
    float m_run = -3.0e38f, l_run = 0.f;

    // ---- staging: 8 x global_load_lds per wave per KVBLK (64 total) ----
    auto stage = [&](int chunk, int buf) {
        const int kv0 = kvbase + chunk * 64;
        unsigned char* base = smem + buf * BUFSZ;
        #pragma unroll
        for (int i = 0; i < 4; i++) {
            const int t = wid * 4 + i;                 // 0..31
            // K fp16 [64 rows][512B]; instr t covers rows 2t,2t+1
            const int krow = 2 * t + h;
            const int ksl  = (lane & 31) ^ (krow & 7);
            gld16(Kf + (size_t)(b * SEQ + kv0 + krow) * DIM + ksl * 8,
                  base + KLDS + t * 1024);
            // V bf16 [256 d][128B]; instr t covers d 8t..8t+7
            const int d   = 8 * t + (lane >> 3);
            const int vsl = (lane & 7) ^ (d & 7);
            gld16(Vt + (size_t)(b * DIM + d) * SEQ + kv0 + vsl * 8,
                  base + VLDS + t * 1024);
        }
    };

    stage(0, 0);
    __syncthreads();

    for (int c = 0; c < 16; c++) {
        const int bf = c & 1;
        if (c + 1 < 16) stage(c + 1, bf ^ 1);

        const unsigned char* kb = smem + bf * BUFSZ;
        const unsigned char* vb = kb + VLDS;

        // ---- two 32-kv sub-tiles; order staggered across waves ----
        #pragma unroll
        for (int ii = 0; ii < 2; ii++) {
            const int st = ii ^ stp;
            // QK^T: A = K rows (kv), B = Q (cols=q)
            f32x16 a;
            #pragma unroll
            for (int j = 0; j < 16; j++) a[j] = 0.f;
            __builtin_amdgcn_s_setprio(1);
            #pragma unroll
            for (int s = 0; s < 16; s++) {
                const int off = (st * 32 + r32) * 512
                              + (((2 * s + h) ^ (r32 & 7)) * 16);
                half8 kf = *(const half8*)(kb + KLDS + off);
                a = MFMAQK(kf, qf[s], a);
            }
            __builtin_amdgcn_s_setprio(0);
            // lane holds S[kv=(j&3)+8*(j>>2)+4h (+32*st)][q=r32] in a[j]
            // (scores are in log2 units: Qf pre-scaled by 1/ln2)

            // online softmax, exp2 domain; pm via 4-deep tree
            float x0 = fmaxf(a[0],  a[1]),  x1 = fmaxf(a[2],  a[3]);
            float x2 = fmaxf(a[4],  a[5]),  x3 = fmaxf(a[6],  a[7]);
            float x4 = fmaxf(a[8],  a[9]),  x5 = fmaxf(a[10], a[11]);
            float x6 = fmaxf(a[12], a[13]), x7 = fmaxf(a[14], a[15]);
            float y0 = fmaxf(x0, x1), y1 = fmaxf(x2, x3);
            float y2 = fmaxf(x4, x5), y3 = fmaxf(x6, x7);
            float pm = fmaxf(fmaxf(y0, y1), fmaxf(y2, y3));
            pm = xhalf_max(pm);
            const bool defer = __all(pm <= m_run + 8.0f) != 0;   // P <= 2^8
            const float mn = defer ? m_run : fmaxf(m_run, pm);
            const float sc = defer ? 1.0f : exp2f(m_run - mn);
            float e[16];
            #pragma unroll
            for (int j = 0; j < 16; j++) e[j] = exp2f(a[j] - mn);
            // ps via 4-deep tree
            float s0 = (e[0] + e[1]) + (e[2] + e[3]);
            float s1 = (e[4] + e[5]) + (e[6] + e[7]);
            float s2 = (e[8] + e[9]) + (e[10] + e[11]);
            float s3 = (e[12] + e[13]) + (e[14] + e[15]);
            float ps = (s0 + s1) + (s2 + s3);
            ps = xhalf_sum(ps);
            l_run = l_run * sc + ps;
            m_run = mn;

            // P -> bf16 B-fragments via cvt_pk + permlane32_swap
            unsigned w[8];
            #pragma unroll
            for (int t = 0; t < 8; t++)
                asm("v_cvt_pk_bf16_f32 %0, %1, %2"
                    : "=v"(w[t]) : "v"(e[2 * t]), "v"(e[2 * t + 1]));
            asm volatile("v_permlane32_swap_b32 %0, %1" : "+v"(w[0]), "+v"(w[2]));
            asm volatile("v_permlane32_swap_b32 %0, %1" : "+v"(w[1]), "+v"(w[3]));
            asm volatile("v_permlane32_swap_b32 %0, %1" : "+v"(w[4]), "+v"(w[6]));
            asm volatile("v_permlane32_swap_b32 %0, %1" : "+v"(w[5]), "+v"(w[7]));
            bf16x8 pA = __builtin_bit_cast(bf16x8, u32x4{w[0], w[1], w[2], w[3]});
            bf16x8 pB = __builtin_bit_cast(bf16x8, u32x4{w[4], w[5], w[6], w[7]});

            // PV: A = V^T (rows=d), B = P; k-slots st*4..st*4+3
            __builtin_amdgcn_s_setprio(1);
            #pragma unroll
            for (int dt = 0; dt < 8; dt++) {
                const int d = dt * 32 + r32;
                const int sw = d & 7;
                bf16x8 v0 = *(const bf16x8*)(vb + d * 128
                               + (((st * 4 + h)     ^ sw) * 16));
                bf16x8 v1 = *(const bf16x8*)(vb + d * 128
                               + (((st * 4 + 2 + h) ^ sw) * 16));
                f32x16 oo = o[dt];
                if (!defer) {
                    #pragma unroll
                    for (int j = 0; j < 16; j++) oo[j] *= sc;
                }
                oo = MFMAPV(v0, pA, oo);
                oo = MFMAPV(v1, pB, oo);
                o[dt] = oo;
            }
            __builtin_amdgcn_s_setprio(0);
        }

        __syncthreads();   // drains vmcnt: prefetch landed; buffers reusable
    }

    // ---- m,l store (m in log2 units; combine uses exp2) ----
    if (h == 0) {
        float2* mlp = (split == 0) ? ml0 : (split == 1) ? ml1
                    : (split == 2) ? ml2 : ml3;
        mlp[qrow0 + wid * 32 + r32] = float2{m_run, l_run};
    }

    // ---- epilogue: LDS transpose (32-d passes) + coalesced bf16 store ----
    unsigned short* oP = (split == 0) ? O0 : (split == 1) ? O1
                       : (split == 2) ? O2 : O3;
    float* T = (float*)smem;   // [256 q][33] f32 = 33 KB
    #pragma unroll
    for (int dt = 0; dt < 8; dt++) {
        __syncthreads();
        #pragma unroll
        for (int j = 0; j < 16; j++) {
            const int dloc = (j & 3) + 8 * (j >> 2) + 4 * h;
            T[(wid * 32 + r32) * 33 + dloc] = o[dt][j];
        }
        __syncthreads();
        #pragma unroll
        for (int rq = 0; rq < 4; rq++) {
            const int q = wid * 32 + rq * 8 + (lane >> 3);
            const float* tr = T + q * 33 + (lane & 7) * 4;
            ushort4t pk;
            #pragma unroll
            for (int r = 0; r < 4; r++) pk[r] = (unsigned short)f2bf(tr[r]);
            *(ushort4t*)(oP + (size_t)(qrow0 + q) * DIM
                         + dt * 32 + (lane & 7) * 4) = pk;
        }
    }
}

// ---------------------------------------------------------------------------
// Kernel 4: merge the four kv-split partials + residual (exp2 domain).
// ---------------------------------------------------------------------------
__global__ __launch_bounds__(256) void combine_kernel(
    const unsigned short* __restrict__ o0, const unsigned short* __restrict__ o1,
    const unsigned short* __restrict__ o2, const unsigned short* __restrict__ o3,
    const float2* __restrict__ ml0, const float2* __restrict__ ml1,
    const float2* __restrict__ ml2, const float2* __restrict__ ml3,
    const float* __restrict__ x, float* __restrict__ out)
{
    int row = blockIdx.x * 4 + (threadIdx.x >> 6);
    int c0  = (threadIdx.x & 63) * 4;
    float2 A = ml0[row], B = ml1[row], C = ml2[row], D = ml3[row];
    float M  = fmaxf(fmaxf(A.x, B.x), fmaxf(C.x, D.x));
    float w0 = exp2f(A.x - M), w1 = exp2f(B.x - M);
    float w2 = exp2f(C.x - M), w3 = exp2f(D.x - M);
    float inv = 1.0f / (w0 * A.y + w1 * B.y + w2 * C.y + w3 * D.y);
    size_t base = (size_t)row * DIM + c0;
    ushort4t u0 = *(const ushort4t*)(o0 + base);
    ushort4t u1 = *(const ushort4t*)(o1 + base);
    ushort4t u2 = *(const ushort4t*)(o2 + base);
    ushort4t u3 = *(const ushort4t*)(o3 + base);
    f32x4    xr = *(const f32x4*)(x + base);
    f32x4 res;
    #pragma unroll
    for (int j = 0; j < 4; j++)
        res[j] = (w0 * bf2f((unsigned)u0[j]) + w1 * bf2f((unsigned)u1[j])
                + w2 * bf2f((unsigned)u2[j]) + w3 * bf2f((unsigned)u3[j])) * inv
                + xr[j];
    *(f32x4*)(out + base) = res;
}

// ---------------------------------------------------------------------------
extern "C" void kernel_launch(void* const* d_in, const int* in_sizes, int n_in,
                              void* d_out, int out_size, void* d_ws, size_t ws_size,
                              hipStream_t stream)
{
    const float* x  = (const float*)d_in[0];
    const float* Wq = (const float*)d_in[1];
    const float* bq = (const float*)d_in[2];
    const float* Wk = (const float*)d_in[3];
    const float* bk = (const float*)d_in[4];
    const float* Wv = (const float*)d_in[5];
    const float* bv = (const float*)d_in[6];
    float* out = (float*)d_out;

    unsigned char* ws = (unsigned char*)d_ws;
    _Float16*       Qf   = (_Float16*)(ws);                      //  8 MB
    _Float16*       Kf   = (_Float16*)(ws +  8388608);           //  8 MB
    unsigned short* Vt   = (unsigned short*)(ws + 16777216);     //  8 MB
    unsigned short* WtHi = (unsigned short*)(ws + 25165824);     // 384 KB
    unsigned short* WtLo = (unsigned short*)(ws + 25559040);     // 384 KB
    unsigned short* O0   = (unsigned short*)(ws + 25952256);     //  8 MB
    unsigned short* O1   = (unsigned short*)(ws + 34340864);     //  8 MB
    unsigned short* O2   = (unsigned short*)(ws + 42729472);     //  8 MB
    unsigned short* O3   = (unsigned short*)(ws + 51118080);     //  8 MB
    float2*         ML0  = (float2*)       (ws + 59506688);
    float2*         ML1  = (float2*)       (ws + 59637760);
    float2*         ML2  = (float2*)       (ws + 59768832);
    float2*         ML3  = (float2*)       (ws + 59899904);
    // total ws use: 60,030,976 bytes

    convert_w_kernel<<<dim3(256, 3), 256, 0, stream>>>(Wq, Wk, Wv, WtHi, WtLo);
    proj_kernel<<<dim3(256, 2), 256, 0, stream>>>(x, WtHi, WtLo, bq, bk, bv,
                                                  Qf, Kf, Vt);
    flash_kernel<<<dim3(64, 4), 512, 0, stream>>>(Qf, Kf, Vt,
                                                  O0, O1, O2, O3,
                                                  ML0, ML1, ML2, ML3);
    combine_kernel<<<4096, 256, 0, stream>>>(O0, O1, O2, O3,
                                             ML0, ML1, ML2, ML3, x, out);
}

// Round 15
// 157.622 us; speedup vs baseline: 1.0760x; 1.0760x over previous
//
#include <hip/hip_runtime.h>
#include <stdint.h>

#define NB   4
#define SEQ  4096
#define DIM  256
#define NROW (NB*SEQ)   // 16384

using bf16x8   = __attribute__((ext_vector_type(8))) __bf16;
using half8    = __attribute__((ext_vector_type(8))) _Float16;
using f32x4    = __attribute__((ext_vector_type(4))) float;
using f32x16   = __attribute__((ext_vector_type(16))) float;
using u32x4    = __attribute__((ext_vector_type(4))) unsigned int;
using ushort4t = __attribute__((ext_vector_type(4))) unsigned short;

#define RLOG2E 1.44269504088896340736f   // 1/ln2, folded into Qf by proj

// RAW exp2 intrinsic -> bare v_exp_f32. R14 lesson: libm exp2f() lowers to
// __ocml_exp2_f32 (denormal-fixup wrapper, ~8 VALU ops) and REGRESSED;
// the builtin is the 1-op form. Args here are <= 8 (defer bound 2^8) and
// underflow to 0 for large-negative — both fine for v_exp_f32.
#define EXP2(x) __builtin_amdgcn_exp2f(x)

__device__ __forceinline__ unsigned f2bf(float f){
    unsigned u = __builtin_bit_cast(unsigned, f);
    return (u + 0x7fffu + ((u >> 16) & 1u)) >> 16;   // RNE to bf16 bits
}
__device__ __forceinline__ float bf2f(unsigned b){
    return __builtin_bit_cast(float, b << 16);
}

#define MFMA(a,b,c)   __builtin_amdgcn_mfma_f32_16x16x32_bf16((a),(b),(c),0,0,0)
#define MFMAQK(a,b,c) __builtin_amdgcn_mfma_f32_32x32x16_f16((a),(b),(c),0,0,0)
#define MFMAPV(a,b,c) __builtin_amdgcn_mfma_f32_32x32x16_bf16((a),(b),(c),0,0,0)

// async global -> LDS, 16 B per lane. LDS dest = wave-uniform base + lane*16.
__device__ __forceinline__ void gld16(const void* g, void* l){
    __builtin_amdgcn_global_load_lds(
        (const __attribute__((address_space(1))) void*)g,
        (__attribute__((address_space(3))) void*)l, 16, 0, 0);
}

// Cross-half (lane i <-> i+32) reduce on the VALU pipe via permlane32_swap.
// R8 lesson: b must be forced into its OWN register (opaque asm) or CSE +
// tied "+v" constraints collapse both operands to one physreg -> in-place
// half-exchange (wrong). After swap(a,b): own value in one reg, cross-half
// value in the other.
__device__ __forceinline__ float xhalf_max(float x){
    unsigned a = __builtin_bit_cast(unsigned, x);
    unsigned b = a;
    asm volatile("" : "+v"(b));                       // force distinct reg
    asm volatile("v_permlane32_swap_b32 %0, %1" : "+v"(a), "+v"(b));
    return fmaxf(__builtin_bit_cast(float, a), __builtin_bit_cast(float, b));
}
__device__ __forceinline__ float xhalf_sum(float x){
    unsigned a = __builtin_bit_cast(unsigned, x);
    unsigned b = a;
    asm volatile("" : "+v"(b));                       // force distinct reg
    asm volatile("v_permlane32_swap_b32 %0, %1" : "+v"(a), "+v"(b));
    return __builtin_bit_cast(float, a) + __builtin_bit_cast(float, b);
}

// ---------------------------------------------------------------------------
// Kernel 1: W[k][n] fp32 -> FRAGMENT-ORDERED split bf16 planes.
//   o = ((((m*2+nh)*8+nt)*8+kc)*64 + lane)*8 + j
// ---------------------------------------------------------------------------
__global__ __launch_bounds__(256) void convert_w_kernel(
    const float* __restrict__ Wq, const float* __restrict__ Wk,
    const float* __restrict__ Wv,
    unsigned short* __restrict__ WtHi, unsigned short* __restrict__ WtLo)
{
    int mat = blockIdx.y;
    const float* W = (mat == 0) ? Wq : (mat == 1 ? Wk : Wv);
    int id = blockIdx.x * 256 + threadIdx.x;     // 0..65535
    int k = id >> 8, n = id & 255;
    float v = W[id];                              // W[k][n], coalesced read
    unsigned hi = f2bf(v);
    unsigned lo = f2bf(v - bf2f(hi));
    int nh = n >> 7, nt = (n >> 4) & 7, q16 = n & 15;
    int kc = k >> 5, g = (k >> 3) & 3, j = k & 7;
    int lane = g * 16 + q16;
    int o = ((((mat * 2 + nh) * 8 + nt) * 8 + kc) * 64 + lane) * 8 + j;
    WtHi[o] = (unsigned short)hi;
    WtLo[o] = (unsigned short)lo;
}

// ---------------------------------------------------------------------------
// Kernel 2: fused QKV projection (3-term bf16 split, fp32 accum).
// W fragments staged per-kc into 48 KB LDS via global_load_lds (R11/R12).
// Q is scaled by 1/ln2 at write -> flash softmax runs in exp2 domain.
// Emits Qf/Kf fp16 [16384][256], Vt bf16 transposed [b][d][s].
// ---------------------------------------------------------------------------
__global__ __launch_bounds__(256) void proj_kernel(
    const float* __restrict__ x,
    const unsigned short* __restrict__ WtHi, const unsigned short* __restrict__ WtLo,
    const float* __restrict__ bq, const float* __restrict__ bk,
    const float* __restrict__ bv,
    _Float16* __restrict__ Qf, _Float16* __restrict__ Kf,
    unsigned short* __restrict__ Vt)
{
    __shared__ __align__(16) unsigned char wsm[49152];   // 48 frag-slots x 1 KB

    const int tid = threadIdx.x, lane = tid & 63, wid = tid >> 6;
    const int g = lane >> 4, q16 = lane & 15;
    const int mbase = blockIdx.x * 64 + wid * 16;
    const int nh = blockIdx.y;

    f32x4 acc[3][8];
    #pragma unroll
    for (int m = 0; m < 3; m++)
        #pragma unroll
        for (int n = 0; n < 8; n++) acc[m][n] = f32x4{0.f, 0.f, 0.f, 0.f};

    const float* xr = x + (mbase + q16) * DIM;

    for (int kc = 0; kc < 8; kc++) {
        __syncthreads();   // previous iteration's LDS reads complete
        // ---- stage this kc's 48 fragment-KB (3 mats x 8 nt x 2 planes) ----
        #pragma unroll
        for (int i = 0; i < 12; i++) {
            const int idx = wid * 12 + i;            // 0..47 = mat*16+nt*2+pl
            const int mat = idx >> 4, nt = (idx >> 1) & 7, pl = idx & 1;
            const size_t fb =
                ((size_t)(((mat * 2 + nh) * 8 + nt) * 8 + kc)) * 512 + lane * 8;
            gld16((pl ? WtLo : WtHi) + fb, wsm + idx * 1024);
        }

        // ---- x split hi/lo (overlaps the DMA) ----
        const float* p = xr + kc * 32 + 8 * g;
        f32x4 va = *(const f32x4*)p;
        f32x4 vb = *(const f32x4*)(p + 4);
        float fv[8] = {va[0], va[1], va[2], va[3], vb[0], vb[1], vb[2], vb[3]};
        unsigned hw[4], lw[4];
        #pragma unroll
        for (int i = 0; i < 4; i++) {
            unsigned h0 = f2bf(fv[2*i]),              h1 = f2bf(fv[2*i+1]);
            unsigned l0 = f2bf(fv[2*i]   - bf2f(h0)), l1 = f2bf(fv[2*i+1] - bf2f(h1));
            hw[i] = h0 | (h1 << 16);
            lw[i] = l0 | (l1 << 16);
        }
        bf16x8 ahi = __builtin_bit_cast(bf16x8, u32x4{hw[0], hw[1], hw[2], hw[3]});
        bf16x8 alo = __builtin_bit_cast(bf16x8, u32x4{lw[0], lw[1], lw[2], lw[3]});

        __syncthreads();   // DMA landed (barrier drains vmcnt)

        #pragma unroll
        for (int mat = 0; mat < 3; mat++) {
            #pragma unroll
            for (int nt = 0; nt < 8; nt++) {
                const int sidx = mat * 16 + nt * 2;
                bf16x8 bh = *(const bf16x8*)(wsm + sidx * 1024 + lane * 16);
                bf16x8 bl = *(const bf16x8*)(wsm + (sidx + 1) * 1024 + lane * 16);
                acc[mat][nt] = MFMA(ahi, bh, acc[mat][nt]);
                acc[mat][nt] = MFMA(ahi, bl, acc[mat][nt]);
                acc[mat][nt] = MFMA(alo, bh, acc[mat][nt]);
            }
        }
    }

    #pragma unroll
    for (int nt = 0; nt < 8; nt++) {
        int ncol = nh * 128 + nt * 16 + q16;
        {   // Q -> fp16, pre-scaled by 1/ln2 (exp2-domain softmax)
            float bb = bq[ncol];
            f32x4 c = acc[0][nt];
            #pragma unroll
            for (int r = 0; r < 4; r++)
                Qf[(size_t)(mbase + 4*g + r) * DIM + ncol] =
                    (_Float16)((c[r] + bb) * RLOG2E);
        }
        {   // K -> fp16
            float bb = bk[ncol];
            f32x4 c = acc[1][nt];
            #pragma unroll
            for (int r = 0; r < 4; r++)
                Kf[(size_t)(mbase + 4*g + r) * DIM + ncol] = (_Float16)(c[r] + bb);
        }
        {   // V -> plain transposed bf16 Vt[b][d][s]
            float bb = bv[ncol];
            f32x4 c = acc[2][nt];
            ushort4t pk;
            #pragma unroll
            for (int r = 0; r < 4; r++) pk[r] = (unsigned short)f2bf(c[r] + bb);
            int m0 = mbase + 4 * g;
            int bat = m0 >> 12, s0 = m0 & 4095;
            *(ushort4t*)(Vt + (size_t)(bat * DIM + ncol) * SEQ + s0) = pk;
        }
    }
}

// ---------------------------------------------------------------------------
// Kernel 3: flash attention — R13 structure (known-best schedule).
// SINGLE change vs R14: exp2f (libm, slow wrapper) -> __builtin_amdgcn_exp2f
// (bare v_exp_f32). Keeps exp2-domain scores + tree reductions.
// SQ_LDS_BANK_CONFLICT == 8388608 is STRUCTURAL (4 extra cy per
// ds_read_b128, m134) — not fixable by swizzle; ignore it.
// ---------------------------------------------------------------------------
#define KLDS  0
#define VLDS  32768
#define BUFSZ 65536

__global__ __launch_bounds__(512, 1) void flash_kernel(
    const _Float16* __restrict__ Qf, const _Float16* __restrict__ Kf,
    const unsigned short* __restrict__ Vt,
    unsigned short* __restrict__ O0, unsigned short* __restrict__ O1,
    unsigned short* __restrict__ O2, unsigned short* __restrict__ O3,
    float2* __restrict__ ml0, float2* __restrict__ ml1,
    float2* __restrict__ ml2, float2* __restrict__ ml3)
{
    __shared__ __align__(16) unsigned char smem[131072];

    const int tid = threadIdx.x, lane = tid & 63, wid = tid >> 6;
    const int r32 = lane & 31, h = lane >> 5;
    const int qrow0 = blockIdx.x * 256;
    const int b = qrow0 >> 12;
    const int split = blockIdx.y;
    const int kvbase = split * 1024;
    const int stp = wid & 1;          // sub-tile phase stagger per wave

    // --- Q fragments: B-operand, col q = r32, k = 16s + 8h + j ---
    half8 qf[16];
    {
        const _Float16* qp = Qf + (size_t)(qrow0 + wid * 32 + r32) * DIM;
        #pragma unroll
        for (int s = 0; s < 16; s++)
            qf[s] = *(const half8*)(qp + s * 16 + h * 8);
    }

    f32x16 o[8];
    #pragma unroll
    for (int i = 0; i < 8; i++)
        #pragma unroll
        for (int j = 0; j < 16; j++) o[i][j] = 0.f;
    float m_run = -3.0e38f, l_run = 0.f;

    // ---- staging: 8 x global_load_lds per wave per KVBLK (64 total) ----
    auto stage = [&](int chunk, int buf) {
        const int kv0 = kvbase + chunk * 64;
        unsigned char* base = smem + buf * BUFSZ;
        #pragma unroll
        for (int i = 0; i < 4; i++) {
            const int t = wid * 4 + i;                 // 0..31
            // K fp16 [64 rows][512B]; instr t covers rows 2t,2t+1
            const int krow = 2 * t + h;
            const int ksl  = (lane & 31) ^ (krow & 7);
            gld16(Kf + (size_t)(b * SEQ + kv0 + krow) * DIM + ksl * 8,
                  base + KLDS + t * 1024);
            // V bf16 [256 d][128B]; instr t covers d 8t..8t+7
            const int d   = 8 * t + (lane >> 3);
            const int vsl = (lane & 7) ^ (d & 7);
            gld16(Vt + (size_t)(b * DIM + d) * SEQ + kv0 + vsl * 8,
                  base + VLDS + t * 1024);
        }
    };

    stage(0, 0);
    __syncthreads();

    for (int c = 0; c < 16; c++) {
        const int bf = c & 1;
        if (c + 1 < 16) stage(c + 1, bf ^ 1);

        const unsigned char* kb = smem + bf * BUFSZ;
        const unsigned char* vb = kb + VLDS;

        // ---- two 32-kv sub-tiles; order staggered across waves ----
        #pragma unroll
        for (int ii = 0; ii < 2; ii++) {
            const int st = ii ^ stp;
            // QK^T: A = K rows (kv), B = Q (cols=q)
            f32x16 a;
            #pragma unroll
            for (int j = 0; j < 16; j++) a[j] = 0.f;
            __builtin_amdgcn_s_setprio(1);
            #pragma unroll
            for (int s = 0; s < 16; s++) {
                const int off = (st * 32 + r32) * 512
                              + (((2 * s + h) ^ (r32 & 7)) * 16);
                half8 kf = *(const half8*)(kb + KLDS + off);
                a = MFMAQK(kf, qf[s], a);
            }
            __builtin_amdgcn_s_setprio(0);
            // lane holds S[kv=(j&3)+8*(j>>2)+4h (+32*st)][q=r32] in a[j]
            // (scores are in log2 units: Qf pre-scaled by 1/ln2)

            // online softmax, exp2 domain; pm via 4-deep tree
            float x0 = fmaxf(a[0],  a[1]),  x1 = fmaxf(a[2],  a[3]);
            float x2 = fmaxf(a[4],  a[5]),  x3 = fmaxf(a[6],  a[7]);
            float x4 = fmaxf(a[8],  a[9]),  x5 = fmaxf(a[10], a[11]);
            float x6 = fmaxf(a[12], a[13]), x7 = fmaxf(a[14], a[15]);
            float y0 = fmaxf(x0, x1), y1 = fmaxf(x2, x3);
            float y2 = fmaxf(x4, x5), y3 = fmaxf(x6, x7);
            float pm = fmaxf(fmaxf(y0, y1), fmaxf(y2, y3));
            pm = xhalf_max(pm);
            const bool defer = __all(pm <= m_run + 8.0f) != 0;   // P <= 2^8
            const float mn = defer ? m_run : fmaxf(m_run, pm);
            const float sc = defer ? 1.0f : EXP2(m_run - mn);
            float e[16];
            #pragma unroll
            for (int j = 0; j < 16; j++) e[j] = EXP2(a[j] - mn);
            // ps via 4-deep tree
            float s0 = (e[0] + e[1]) + (e[2] + e[3]);
            float s1 = (e[4] + e[5]) + (e[6] + e[7]);
            float s2 = (e[8] + e[9]) + (e[10] + e[11]);
            float s3 = (e[12] + e[13]) + (e[14] + e[15]);
            float ps = (s0 + s1) + (s2 + s3);
            ps = xhalf_sum(ps);
            l_run = l_run * sc + ps;
            m_run = mn;

            // P -> bf16 B-fragments via cvt_pk + permlane32_swap
            unsigned w[8];
            #pragma unroll
            for (int t = 0; t < 8; t++)
                asm("v_cvt_pk_bf16_f32 %0, %1, %2"
                    : "=v"(w[t]) : "v"(e[2 * t]), "v"(e[2 * t + 1]));
            asm volatile("v_permlane32_swap_b32 %0, %1" : "+v"(w[0]), "+v"(w[2]));
            asm volatile("v_permlane32_swap_b32 %0, %1" : "+v"(w[1]), "+v"(w[3]));
            asm volatile("v_permlane32_swap_b32 %0, %1" : "+v"(w[4]), "+v"(w[6]));
            asm volatile("v_permlane32_swap_b32 %0, %1" : "+v"(w[5]), "+v"(w[7]));
            bf16x8 pA = __builtin_bit_cast(bf16x8, u32x4{w[0], w[1], w[2], w[3]});
            bf16x8 pB = __builtin_bit_cast(bf16x8, u32x4{w[4], w[5], w[6], w[7]});

            // PV: A = V^T (rows=d), B = P; k-slots st*4..st*4+3
            __builtin_amdgcn_s_setprio(1);
            #pragma unroll
            for (int dt = 0; dt < 8; dt++) {
                const int d = dt * 32 + r32;
                const int sw = d & 7;
                bf16x8 v0 = *(const bf16x8*)(vb + d * 128
                               + (((st * 4 + h)     ^ sw) * 16));
                bf16x8 v1 = *(const bf16x8*)(vb + d * 128
                               + (((st * 4 + 2 + h) ^ sw) * 16));
                f32x16 oo = o[dt];
                if (!defer) {
                    #pragma unroll
                    for (int j = 0; j < 16; j++) oo[j] *= sc;
                }
                oo = MFMAPV(v0, pA, oo);
                oo = MFMAPV(v1, pB, oo);
                o[dt] = oo;
            }
            __builtin_amdgcn_s_setprio(0);
        }

        __syncthreads();   // drains vmcnt: prefetch landed; buffers reusable
    }

    // ---- m,l store (m in log2 units; combine uses exp2) ----
    if (h == 0) {
        float2* mlp = (split == 0) ? ml0 : (split == 1) ? ml1
                    : (split == 2) ? ml2 : ml3;
        mlp[qrow0 + wid * 32 + r32] = float2{m_run, l_run};
    }

    // ---- epilogue: LDS transpose (32-d passes) + coalesced bf16 store ----
    unsigned short* oP = (split == 0) ? O0 : (split == 1) ? O1
                       : (split == 2) ? O2 : O3;
    float* T = (float*)smem;   // [256 q][33] f32 = 33 KB
    #pragma unroll
    for (int dt = 0; dt < 8; dt++) {
        __syncthreads();
        #pragma unroll
        for (int j = 0; j < 16; j++) {
            const int dloc = (j & 3) + 8 * (j >> 2) + 4 * h;
            T[(wid * 32 + r32) * 33 + dloc] = o[dt][j];
        }
        __syncthreads();
        #pragma unroll
        for (int rq = 0; rq < 4; rq++) {
            const int q = wid * 32 + rq * 8 + (lane >> 3);
            const float* tr = T + q * 33 + (lane & 7) * 4;
            ushort4t pk;
            #pragma unroll
            for (int r = 0; r < 4; r++) pk[r] = (unsigned short)f2bf(tr[r]);
            *(ushort4t*)(oP + (size_t)(qrow0 + q) * DIM
                         + dt * 32 + (lane & 7) * 4) = pk;
        }
    }
}

// ---------------------------------------------------------------------------
// Kernel 4: merge the four kv-split partials + residual (exp2 domain).
// ---------------------------------------------------------------------------
__global__ __launch_bounds__(256) void combine_kernel(
    const unsigned short* __restrict__ o0, const unsigned short* __restrict__ o1,
    const unsigned short* __restrict__ o2, const unsigned short* __restrict__ o3,
    const float2* __restrict__ ml0, const float2* __restrict__ ml1,
    const float2* __restrict__ ml2, const float2* __restrict__ ml3,
    const float* __restrict__ x, float* __restrict__ out)
{
    int row = blockIdx.x * 4 + (threadIdx.x >> 6);
    int c0  = (threadIdx.x & 63) * 4;
    float2 A = ml0[row], B = ml1[row], C = ml2[row], D = ml3[row];
    float M  = fmaxf(fmaxf(A.x, B.x), fmaxf(C.x, D.x));
    float w0 = __builtin_amdgcn_exp2f(A.x - M), w1 = __builtin_amdgcn_exp2f(B.x - M);
    float w2 = __builtin_amdgcn_exp2f(C.x - M), w3 = __builtin_amdgcn_exp2f(D.x - M);
    float inv = 1.0f / (w0 * A.y + w1 * B.y + w2 * C.y + w3 * D.y);
    size_t base = (size_t)row * DIM + c0;
    ushort4t u0 = *(const ushort4t*)(o0 + base);
    ushort4t u1 = *(const ushort4t*)(o1 + base);
    ushort4t u2 = *(const ushort4t*)(o2 + base);
    ushort4t u3 = *(const ushort4t*)(o3 + base);
    f32x4    xr = *(const f32x4*)(x + base);
    f32x4 res;
    #pragma unroll
    for (int j = 0; j < 4; j++)
        res[j] = (w0 * bf2f((unsigned)u0[j]) + w1 * bf2f((unsigned)u1[j])
                + w2 * bf2f((unsigned)u2[j]) + w3 * bf2f((unsigned)u3[j])) * inv
                + xr[j];
    *(f32x4*)(out + base) = res;
}

// ---------------------------------------------------------------------------
extern "C" void kernel_launch(void* const* d_in, const int* in_sizes, int n_in,
                              void* d_out, int out_size, void* d_ws, size_t ws_size,
                              hipStream_t stream)
{
    const float* x  = (const float*)d_in[0];
    const float* Wq = (const float*)d_in[1];
    const float* bq = (const float*)d_in[2];
    const float* Wk = (const float*)d_in[3];
    const float* bk = (const float*)d_in[4];
    const float* Wv = (const float*)d_in[5];
    const float* bv = (const float*)d_in[6];
    float* out = (float*)d_out;

    unsigned char* ws = (unsigned char*)d_ws;
    _Float16*       Qf   = (_Float16*)(ws);                      //  8 MB
    _Float16*       Kf   = (_Float16*)(ws +  8388608);           //  8 MB
    unsigned short* Vt   = (unsigned short*)(ws + 16777216);     //  8 MB
    unsigned short* WtHi = (unsigned short*)(ws + 25165824);     // 384 KB
    unsigned short* WtLo = (unsigned short*)(ws + 25559040);     // 384 KB
    unsigned short* O0   = (unsigned short*)(ws + 25952256);     //  8 MB
    unsigned short* O1   = (unsigned short*)(ws + 34340864);     //  8 MB
    unsigned short* O2   = (unsigned short*)(ws + 42729472);     //  8 MB
    unsigned short* O3   = (unsigned short*)(ws + 51118080);     //  8 MB
    float2*         ML0  = (float2*)       (ws + 59506688);
    float2*         ML1  = (float2*)       (ws + 59637760);
    float2*         ML2  = (float2*)       (ws + 59768832);
    float2*         ML3  = (float2*)       (ws + 59899904);
    // total ws use: 60,030,976 bytes

    convert_w_kernel<<<dim3(256, 3), 256, 0, stream>>>(Wq, Wk, Wv, WtHi, WtLo);
    proj_kernel<<<dim3(256, 2), 256, 0, stream>>>(x, WtHi, WtLo, bq, bk, bv,
                                                  Qf, Kf, Vt);
    flash_kernel<<<dim3(64, 4), 512, 0, stream>>>(Qf, Kf, Vt,
                                                  O0, O1, O2, O3,
                                                  ML0, ML1, ML2, ML3);
    combine_kernel<<<4096, 256, 0, stream>>>(O0, O1, O2, O3,
                                             ML0, ML1, ML2, ML3, x, out);
}